// Round 5
// baseline (164.018 us; speedup 1.0000x reference)
//
#include <hip/hip_runtime.h>

// Problem constants (B,C,T,H,HI) = (256, 64, 512, 8, 3)
constexpr int Tn = 512;
constexpr int Cn = 64;
constexpr int NS = 16384;   // sequences = B*C; acc planes are [t][seq]

// ds_swizzle with compile-time pattern (BitMode). Crossbar lane permute on the
// LDS pipe — does NOT consume VALU cycles, no bank conflicts.
template<int OFF>
__device__ __forceinline__ float swzf(float v) {
    int i = __builtin_bit_cast(int, v);
    i = __builtin_amdgcn_ds_swizzle(i, OFF);
    return __builtin_bit_cast(float, i);
}

// One recurrence step, octet decomposition. Lane r of the octet owns hidden
// row r. Broadcast all 8 h values within the octet (lane' = (lane&0x18)|j),
// FMA into 3 accumulation trees, relu, then octet xor-reduce of U_r*h_r.
// Stores the reduced dot to *op, advances op by SGN NS.
#define OSTEP(xv, mv, dv, SGN) do {                                   \
    float t0 = swzf<0x18>(h);                                         \
    float t1 = swzf<0x38>(h);                                         \
    float t2 = swzf<0x58>(h);                                         \
    float t3 = swzf<0x78>(h);                                         \
    float a = fmaf(Vr0, (xv), cb);                                    \
    float b = Vr1 * (mv);                                             \
    float e = Vr2 * (dv);                                             \
    a = fmaf(W0, t0, a);  b = fmaf(W1, t1, b);  e = fmaf(W2, t2, e);  \
    t0 = swzf<0x98>(h);                                               \
    t1 = swzf<0xB8>(h);                                               \
    t2 = swzf<0xD8>(h);                                               \
    float t7 = swzf<0xF8>(h);                                         \
    a = fmaf(W3, t3, a);                                              \
    b = fmaf(W4, t0, b);  e = fmaf(W5, t1, e);                        \
    a = fmaf(W6, t2, a);  b = fmaf(W7, t7, b);                        \
    h = fmaxf(a + (b + e), 0.f);                                      \
    float p = Ur * h;                                                 \
    p += swzf<0x041F>(p);                                             \
    p += swzf<0x081F>(p);                                             \
    p += swzf<0x101F>(p);                                             \
    *op = p;                                                          \
    op SGN NS;                                                        \
} while (0)

// Forward 4-step group: carry holds the u=4g-1 sample; float4 covers u=4g..4g+3.
#define GRP_F(X4, M4, D4) do {                                        \
    OSTEP(cx, cm, cd, +=);                                            \
    OSTEP((X4).x, (M4).x, (D4).x, +=);                                \
    OSTEP((X4).y, (M4).y, (D4).y, +=);                                \
    OSTEP((X4).z, (M4).z, (D4).z, +=);                                \
    cx = (X4).w; cm = (M4).w; cd = (D4).w;                            \
} while (0)

// Backward 4-step group: carry holds the u=512-4g sample; float4 covers u=508-4g..511-4g.
#define GRP_B(X4, M4, D4) do {                                        \
    OSTEP(cx, cm, cd, -=);                                            \
    OSTEP((X4).w, (M4).w, (D4).w, -=);                                \
    OSTEP((X4).z, (M4).z, (D4).z, -=);                                \
    OSTEP((X4).y, (M4).y, (D4).y, -=);                                \
    cx = (X4).x; cm = (M4).x; cd = (D4).x;                            \
} while (0)

// Bidirectional per-channel RNN scan, octet decomposition:
// 8 lanes per (sequence, direction); lane r owns hidden row r (scalar h).
// Cross-lane h exchange via ds_swizzle broadcasts (LDS pipe, overlaps VALU).
// 262144 threads = 4096 waves = 4 waves/SIMD.
// Writes acc[t*NS + seq] = U-half · h(t), t-major.
__global__ __launch_bounds__(256, 4) void mrnn_scan(
    const float* __restrict__ x, const float* __restrict__ m, const float* __restrict__ d,
    const float* __restrict__ Wf, const float* __restrict__ Vf, const float* __restrict__ cf,
    const float* __restrict__ Wb, const float* __restrict__ Vb, const float* __restrict__ cbk,
    const float* __restrict__ U, float* __restrict__ accF, float* __restrict__ accB)
{
    const int g   = blockIdx.x * blockDim.x + threadIdx.x;
    const int r   = g & 7;          // owned hidden row
    const int td  = g >> 3;         // (dir, seq)
    const int dir = td >> 14;       // 0 = forward, 1 = backward
    const int seq = td & 16383;     // b*64 + c
    const int c   = seq & 63;
    const long base = (long)seq * Tn;

    const float* W  = dir ? Wb  : Wf;
    const float* V  = dir ? Vb  : Vf;
    const float* cc = dir ? cbk : cf;

    // Per-lane weights: row r of this channel's W/V/c, plus U entry.
    const float* Wr = W + c*64 + r*8;
    const float W0 = Wr[0], W1 = Wr[1], W2 = Wr[2], W3 = Wr[3];
    const float W4 = Wr[4], W5 = Wr[5], W6 = Wr[6], W7 = Wr[7];
    const float Vr0 = V[c*24 + r*3 + 0];
    const float Vr1 = V[c*24 + r*3 + 1];
    const float Vr2 = V[c*24 + r*3 + 2];
    const float cb  = cc[c*8 + r];
    const float Ur  = U[c*16 + dir*8 + r];

    float h = 0.f;
    float cx, cm, cd;
    const float4* x4 = (const float4*)(x + base);
    const float4* m4 = (const float4*)(m + base);
    const float4* d4 = (const float4*)(d + base);
    float* op = (dir ? accB : accF) + seq;   // element stride NS per time step

    if (dir == 0) {
        // forward: step t uses u = max(t-1,0); group g covers t=4g..4g+3
        float4 Ax = x4[0], Am = m4[0], Ad = d4[0];
        float4 Bx = x4[1], Bm = m4[1], Bd = d4[1];
        cx = Ax.x; cm = Am.x; cd = Ad.x;       // u=0 for t=0
        #pragma unroll 1
        for (int i = 0; i < 63; ++i) {
            float4 Txq = x4[2*i+2], Tmq = m4[2*i+2], Tdq = d4[2*i+2];
            GRP_F(Ax, Am, Ad);                 // group 2i
            float4 Uxq = x4[2*i+3], Umq = m4[2*i+3], Udq = d4[2*i+3];
            GRP_F(Bx, Bm, Bd);                 // group 2i+1
            Ax = Txq; Am = Tmq; Ad = Tdq;
            Bx = Uxq; Bm = Umq; Bd = Udq;
        }
        GRP_F(Ax, Am, Ad);                     // group 126
        GRP_F(Bx, Bm, Bd);                     // group 127
    } else {
        // backward: pos descends 511..0; group g covers pos 511-4g..508-4g,
        // uses float4 block 127-g (u = pos+1, clamped at 511 for pos=511)
        op += 511 * NS;
        float4 Ax = x4[127], Am = m4[127], Ad = d4[127];
        float4 Bx = x4[126], Bm = m4[126], Bd = d4[126];
        cx = Ax.w; cm = Am.w; cd = Ad.w;       // u=511 for pos=511 (s=0)
        #pragma unroll 1
        for (int i = 0; i < 63; ++i) {
            float4 Txq = x4[125-2*i], Tmq = m4[125-2*i], Tdq = d4[125-2*i];
            GRP_B(Ax, Am, Ad);                 // group 2i
            float4 Uxq = x4[124-2*i], Umq = m4[124-2*i], Udq = d4[124-2*i];
            GRP_B(Bx, Bm, Bd);                 // group 2i+1
            Ax = Txq; Am = Tmq; Ad = Tdq;
            Bx = Uxq; Bm = Umq; Bd = Udq;
        }
        GRP_B(Ax, Am, Ad);                     // group 126
        GRP_B(Bx, Bm, Bd);                     // group 127
    }
}

// Combine + cross-channel bottleneck MLP. One thread per (b,t).
// x_est = relu(accF + accB + c0); h(3) = relu(V1·x_est + V2·m + Uz·x + U_b);
// out = W_w·h + W_b.
__global__ __launch_bounds__(256, 2) void mrnn_mix(
    const float* __restrict__ x, const float* __restrict__ m,
    const float* __restrict__ accF, const float* __restrict__ accB,
    const float* __restrict__ c0, const float* __restrict__ V1w,
    const float* __restrict__ V2w, const float* __restrict__ Uw,
    const float* __restrict__ Ub, const float* __restrict__ Ww,
    const float* __restrict__ Wbias, float* __restrict__ out)
{
    const int bt = blockIdx.x * 256 + threadIdx.x;   // 0..131071
    const int b = bt >> 9;
    const int t = bt & 511;

    const float4* aF4 = (const float4*)(accF + (size_t)t * NS + b * Cn);
    const float4* aB4 = (const float4*)(accB + (size_t)t * NS + b * Cn);
    const size_t xb = (size_t)b * (Cn * Tn) + t;

    float h0 = Ub[0], h1 = Ub[1], h2 = Ub[2];
    #pragma unroll
    for (int c4 = 0; c4 < 16; ++c4) {
        const float4 fa = aF4[c4];
        const float4 fb = aB4[c4];
        const float fav[4] = {fa.x, fa.y, fa.z, fa.w};
        const float fbv[4] = {fb.x, fb.y, fb.z, fb.w};
        #pragma unroll
        for (int j = 0; j < 4; ++j) {
            const int cch = 4*c4 + j;
            const float xe = fmaxf(fav[j] + fbv[j] + c0[cch], 0.f);
            const float mv = m[xb + (size_t)cch * Tn];
            const float xv = x[xb + (size_t)cch * Tn];
            const float u0 = (cch == 0) ? 0.f : Uw[0*Cn + cch];
            const float u1 = (cch == 1) ? 0.f : Uw[1*Cn + cch];
            const float u2 = (cch == 2) ? 0.f : Uw[2*Cn + cch];
            h0 += V1w[0*Cn + cch]*xe + V2w[0*Cn + cch]*mv + u0*xv;
            h1 += V1w[1*Cn + cch]*xe + V2w[1*Cn + cch]*mv + u1*xv;
            h2 += V1w[2*Cn + cch]*xe + V2w[2*Cn + cch]*mv + u2*xv;
        }
    }
    h0 = fmaxf(h0, 0.f); h1 = fmaxf(h1, 0.f); h2 = fmaxf(h2, 0.f);

    float* opt = out + (size_t)b * (Cn * Tn) + t;
    #pragma unroll
    for (int cch = 0; cch < Cn; ++cch) {
        opt[(size_t)cch * Tn] = Wbias[cch] + Ww[cch*3 + 0]*h0 + Ww[cch*3 + 1]*h1 + Ww[cch*3 + 2]*h2;
    }
}

extern "C" void kernel_launch(void* const* d_in, const int* in_sizes, int n_in,
                              void* d_out, int out_size, void* d_ws, size_t ws_size,
                              hipStream_t stream)
{
    const float* x   = (const float*)d_in[0];
    const float* m   = (const float*)d_in[1];
    const float* d   = (const float*)d_in[2];
    const float* Wf  = (const float*)d_in[3];
    const float* Vf  = (const float*)d_in[4];
    const float* cf  = (const float*)d_in[5];
    const float* Wb  = (const float*)d_in[6];
    const float* Vb  = (const float*)d_in[7];
    const float* cb  = (const float*)d_in[8];
    const float* U   = (const float*)d_in[9];
    const float* c0  = (const float*)d_in[10];
    const float* V1w = (const float*)d_in[11];
    const float* V2w = (const float*)d_in[12];
    const float* Uw  = (const float*)d_in[13];
    const float* Ub  = (const float*)d_in[14];
    const float* Ww  = (const float*)d_in[15];
    const float* Wb_ = (const float*)d_in[16];
    float* out = (float*)d_out;

    // Workspace: accF and accB planes, each T*NS floats (33.5 MB), t-major.
    float* accF = (float*)d_ws;
    float* accB = accF + (size_t)Tn * NS;

    // 8 lanes * 16384 sequences * 2 directions = 262144 threads
    mrnn_scan<<<1024, 256, 0, stream>>>(x, m, d, Wf, Vf, cf, Wb, Vb, cb, U, accF, accB);
    // one thread per (b,t) = 131072 threads
    mrnn_mix<<<512, 256, 0, stream>>>(x, m, accF, accB, c0, V1w, V2w, Uw, Ub, Ww, Wb_, out);
}

// Round 6
// 162.746 us; speedup vs baseline: 1.0078x; 1.0078x over previous
//
#include <hip/hip_runtime.h>

// Problem constants (B,C,T,H,HI) = (256, 64, 512, 8, 3)
constexpr int Tn = 512;
constexpr int Cn = 64;
constexpr int NS = 16384;   // sequences = B*C
// acc planes: [tc=t>>2][c][b][t&3] : idx = tc*65536 + c*1024 + b*4 + (t&3)

typedef __attribute__((ext_vector_type(8))) short short8;   // bf16x8 MFMA frag
typedef __attribute__((ext_vector_type(4))) float f32x4;
typedef __attribute__((ext_vector_type(4))) int   i32x4;

__device__ __forceinline__ unsigned cvt_pk_bf16(float lo, float hi) {
    unsigned r;
    asm("v_cvt_pk_bf16_f32 %0, %1, %2" : "=v"(r) : "v"(lo), "v"(hi));
    return r;
}
// xor-16 lane exchange on the LDS crossbar (off the recurrence critical path)
__device__ __forceinline__ float swz_xor16(float v) {
    int i = __builtin_bit_cast(int, v);
    i = __builtin_amdgcn_ds_swizzle(i, 0x401F);
    return __builtin_bit_cast(float, i);
}

// Forward 4-step group: carry holds u=4g-1 sample; float4 covers u=4g..4g+3.
#define GRP_F(X4, M4, P4) do {                                        \
    v0 = step(cx, cm, cd);                                            \
    v1 = step((X4).x, (M4).x, (P4).x);                                \
    v2 = step((X4).y, (M4).y, (P4).y);                                \
    v3 = step((X4).z, (M4).z, (P4).z);                                \
    if (doSt) *(float4*)op = make_float4(v0, v1, v2, v3);             \
    op += 65536;                                                      \
    cx = (X4).w; cm = (M4).w; cd = (P4).w;                            \
} while (0)

// Backward 4-step group: positions pos=4g'+3..4g' (descending s); carry = next u.
#define GRP_B(X4, M4, P4) do {                                        \
    v3 = step(cx, cm, cd);                                            \
    v2 = step((X4).w, (M4).w, (P4).w);                                \
    v1 = step((X4).z, (M4).z, (P4).z);                                \
    v0 = step((X4).y, (M4).y, (P4).y);                                \
    if (doSt) *(float4*)op = make_float4(v0, v1, v2, v3);             \
    op -= 65536;                                                      \
    cx = (X4).x; cm = (M4).x; cd = (P4).x;                            \
} while (0)

// Bidirectional per-channel RNN scan via MFMA.
// One wave = one (dir, channel, batch-group-of-16). Step:
//   h' = relu( W_aug(16x32-slots) . [h; x; m; d; 1] )  -- one mfma_16x16x32_bf16
// Slot scheme (mapping-agnostic, see analysis): A/B use elems i=0..3 per lane
// group g as 16 abstract k-slots; g0 = W[:,0:4] x h[0:4] (G0's own D regs),
// g1 = W[:,4:8] x h[4:8] (G1's own D), g2 = (V0,V1,V2,c) x (x,m,d,1), g3 = 0.
__global__ __launch_bounds__(256, 2) void mrnn_scan(
    const float* __restrict__ x, const float* __restrict__ m, const float* __restrict__ d,
    const float* __restrict__ Wf, const float* __restrict__ Vf, const float* __restrict__ cf,
    const float* __restrict__ Wb, const float* __restrict__ Vb, const float* __restrict__ cbk,
    const float* __restrict__ Uu, float* __restrict__ accF, float* __restrict__ accB)
{
    const int w    = blockIdx.x * 4 + (threadIdx.x >> 6);  // 0..2047
    const int bg   = w & 15;
    const int c    = (w >> 4) & 63;
    const int dir  = w >> 10;
    const int lane = threadIdx.x & 63;
    const int col  = lane & 15;        // batch within group; also A row
    const int grp  = lane >> 4;
    const int b    = bg * 16 + col;

    const float* W  = dir ? Wb  : Wf;
    const float* V  = dir ? Vb  : Vf;
    const float* cc = dir ? cbk : cf;

    // ---- A fragment (constant over steps) ----
    float a0 = 0.f, a1 = 0.f, a2 = 0.f, a3 = 0.f;
    {
        const int row = col;
        if (row < 8) {
            if (grp == 0) {
                const float* Wc = W + c*64 + row*8;
                a0 = Wc[0]; a1 = Wc[1]; a2 = Wc[2]; a3 = Wc[3];
            } else if (grp == 1) {
                const float* Wc = W + c*64 + row*8;
                a0 = Wc[4]; a1 = Wc[5]; a2 = Wc[6]; a3 = Wc[7];
            } else if (grp == 2) {
                a0 = V[c*24 + row*3 + 0];
                a1 = V[c*24 + row*3 + 1];
                a2 = V[c*24 + row*3 + 2];
                a3 = cc[c*8 + row];
            }
        }
    }
    i32x4 ai = { (int)cvt_pk_bf16(a0, a1), (int)cvt_pk_bf16(a2, a3), 0, 0 };
    const short8 Afrag = __builtin_bit_cast(short8, ai);

    // ---- U entries for this lane's hidden rows ----
    float U0 = 0.f, U1 = 0.f, U2 = 0.f, U3 = 0.f;
    if (grp < 2) {
        const float* Uc = Uu + c*16 + dir*8 + grp*4;
        U0 = Uc[0]; U1 = Uc[1]; U2 = Uc[2]; U3 = Uc[3];
    }

    const bool isG2 = (grp == 2);
    const bool isG3 = (grp == 3);
    const bool doSt = (lane < 16);

    const f32x4 z4 = {0.f, 0.f, 0.f, 0.f};
    f32x4 hS = z4;    // h state: G0 rows 0-3, G1 rows 4-7 (others 0)

    // One recurrence step; returns the xor16-reduced U·h (valid on lanes 0-31).
    auto step = [&](float xv, float mv, float dv) -> float {
        float s0 = isG2 ? xv   : hS[0];
        float s1 = isG2 ? mv   : hS[1];
        float s2 = isG2 ? dv   : hS[2];
        float s3 = isG2 ? 1.0f : hS[3];
        unsigned b01 = cvt_pk_bf16(s0, s1);
        unsigned b23 = cvt_pk_bf16(s2, s3);
        b01 = isG3 ? 0u : b01;
        b23 = isG3 ? 0u : b23;
        i32x4 bi = { (int)b01, (int)b23, 0, 0 };
        short8 Bfrag = __builtin_bit_cast(short8, bi);
        f32x4 Dn = __builtin_amdgcn_mfma_f32_16x16x32_bf16(Afrag, Bfrag, z4, 0, 0, 0);
        Dn[0] = fmaxf(Dn[0], 0.f);
        Dn[1] = fmaxf(Dn[1], 0.f);
        Dn[2] = fmaxf(Dn[2], 0.f);
        Dn[3] = fmaxf(Dn[3], 0.f);
        hS = Dn;
        float p = U0*Dn[0] + U1*Dn[1] + U2*Dn[2] + U3*Dn[3];
        return p + swz_xor16(p);
    };

    const float4* x4p = (const float4*)(x + ((size_t)b * Cn + c) * Tn);
    const float4* m4p = (const float4*)(m + ((size_t)b * Cn + c) * Tn);
    const float4* d4p = (const float4*)(d + ((size_t)b * Cn + c) * Tn);
    float* op = (dir ? accB : accF) + c*1024 + (bg*16 + col)*4;

    float cx, cm, cd, v0, v1, v2, v3;

    if (dir == 0) {
        // forward: step t uses u=max(t-1,0); 4 groups in flight (16-step prefetch)
        float4 X0 = x4p[0], X1 = x4p[1], X2 = x4p[2], X3 = x4p[3];
        float4 M0 = m4p[0], M1 = m4p[1], M2 = m4p[2], M3 = m4p[3];
        float4 P0 = d4p[0], P1 = d4p[1], P2 = d4p[2], P3 = d4p[3];
        cx = X0.x; cm = M0.x; cd = P0.x;
        #pragma unroll 1
        for (int i = 0; i < 31; ++i) {
            float4 tX, tM, tP;
            tX = x4p[4*i+4]; tM = m4p[4*i+4]; tP = d4p[4*i+4];
            GRP_F(X0, M0, P0);  X0 = tX; M0 = tM; P0 = tP;
            tX = x4p[4*i+5]; tM = m4p[4*i+5]; tP = d4p[4*i+5];
            GRP_F(X1, M1, P1);  X1 = tX; M1 = tM; P1 = tP;
            tX = x4p[4*i+6]; tM = m4p[4*i+6]; tP = d4p[4*i+6];
            GRP_F(X2, M2, P2);  X2 = tX; M2 = tM; P2 = tP;
            tX = x4p[4*i+7]; tM = m4p[4*i+7]; tP = d4p[4*i+7];
            GRP_F(X3, M3, P3);  X3 = tX; M3 = tM; P3 = tP;
        }
        GRP_F(X0, M0, P0); GRP_F(X1, M1, P1);
        GRP_F(X2, M2, P2); GRP_F(X3, M3, P3);
    } else {
        // backward: s ascending, pos=511-s descending; u=(s==0?511:512-s)
        op += 127 * 65536;
        float4 X0 = x4p[127], X1 = x4p[126], X2 = x4p[125], X3 = x4p[124];
        float4 M0 = m4p[127], M1 = m4p[126], M2 = m4p[125], M3 = m4p[124];
        float4 P0 = d4p[127], P1 = d4p[126], P2 = d4p[125], P3 = d4p[124];
        cx = X0.w; cm = M0.w; cd = P0.w;
        #pragma unroll 1
        for (int i = 0; i < 31; ++i) {
            float4 tX, tM, tP;
            tX = x4p[123-4*i]; tM = m4p[123-4*i]; tP = d4p[123-4*i];
            GRP_B(X0, M0, P0);  X0 = tX; M0 = tM; P0 = tP;
            tX = x4p[122-4*i]; tM = m4p[122-4*i]; tP = d4p[122-4*i];
            GRP_B(X1, M1, P1);  X1 = tX; M1 = tM; P1 = tP;
            tX = x4p[121-4*i]; tM = m4p[121-4*i]; tP = d4p[121-4*i];
            GRP_B(X2, M2, P2);  X2 = tX; M2 = tM; P2 = tP;
            tX = x4p[120-4*i]; tM = m4p[120-4*i]; tP = d4p[120-4*i];
            GRP_B(X3, M3, P3);  X3 = tX; M3 = tM; P3 = tP;
        }
        GRP_B(X0, M0, P0); GRP_B(X1, M1, P1);
        GRP_B(X2, M2, P2); GRP_B(X3, M3, P3);
    }
}

// Combine + cross-channel bottleneck MLP. One thread per (b,t).
// x_est = relu(accF + accB + c0); h(3) = relu(V1·x_est + V2·m + Uz·x + U_b);
// out = W_w·h + W_b.
__global__ __launch_bounds__(256, 2) void mrnn_mix(
    const float* __restrict__ x, const float* __restrict__ m,
    const float* __restrict__ accF, const float* __restrict__ accB,
    const float* __restrict__ c0, const float* __restrict__ V1w,
    const float* __restrict__ V2w, const float* __restrict__ Uw,
    const float* __restrict__ Ub, const float* __restrict__ Ww,
    const float* __restrict__ Wbias, float* __restrict__ out)
{
    const int bt = blockIdx.x * 256 + threadIdx.x;   // 0..131071
    const int b = bt >> 9;
    const int t = bt & 511;
    const int tq = t >> 2, t4 = t & 3;

    const float* aF = accF + (size_t)tq*65536 + b*4 + t4;   // +c*1024 per channel
    const float* aB = accB + (size_t)tq*65536 + b*4 + t4;
    const size_t xb = (size_t)b * (Cn * Tn) + t;

    float h0 = Ub[0], h1 = Ub[1], h2 = Ub[2];
    #pragma unroll 16
    for (int cch = 0; cch < Cn; ++cch) {
        const float xe = fmaxf(aF[cch*1024] + aB[cch*1024] + c0[cch], 0.f);
        const float mv = m[xb + (size_t)cch * Tn];
        const float xv = x[xb + (size_t)cch * Tn];
        const float u0 = (cch == 0) ? 0.f : Uw[0*Cn + cch];
        const float u1 = (cch == 1) ? 0.f : Uw[1*Cn + cch];
        const float u2 = (cch == 2) ? 0.f : Uw[2*Cn + cch];
        h0 += V1w[0*Cn + cch]*xe + V2w[0*Cn + cch]*mv + u0*xv;
        h1 += V1w[1*Cn + cch]*xe + V2w[1*Cn + cch]*mv + u1*xv;
        h2 += V1w[2*Cn + cch]*xe + V2w[2*Cn + cch]*mv + u2*xv;
    }
    h0 = fmaxf(h0, 0.f); h1 = fmaxf(h1, 0.f); h2 = fmaxf(h2, 0.f);

    float* opt = out + (size_t)b * (Cn * Tn) + t;
    #pragma unroll
    for (int cch = 0; cch < Cn; ++cch) {
        opt[(size_t)cch * Tn] = Wbias[cch] + Ww[cch*3 + 0]*h0 + Ww[cch*3 + 1]*h1 + Ww[cch*3 + 2]*h2;
    }
}

extern "C" void kernel_launch(void* const* d_in, const int* in_sizes, int n_in,
                              void* d_out, int out_size, void* d_ws, size_t ws_size,
                              hipStream_t stream)
{
    const float* x   = (const float*)d_in[0];
    const float* m   = (const float*)d_in[1];
    const float* d   = (const float*)d_in[2];
    const float* Wf  = (const float*)d_in[3];
    const float* Vf  = (const float*)d_in[4];
    const float* cf  = (const float*)d_in[5];
    const float* Wb  = (const float*)d_in[6];
    const float* Vb  = (const float*)d_in[7];
    const float* cb  = (const float*)d_in[8];
    const float* U   = (const float*)d_in[9];
    const float* c0  = (const float*)d_in[10];
    const float* V1w = (const float*)d_in[11];
    const float* V2w = (const float*)d_in[12];
    const float* Uw  = (const float*)d_in[13];
    const float* Ub  = (const float*)d_in[14];
    const float* Ww  = (const float*)d_in[15];
    const float* Wb_ = (const float*)d_in[16];
    float* out = (float*)d_out;

    // Workspace: accF and accB planes, each Tn*NS floats (33.5 MB).
    float* accF = (float*)d_ws;
    float* accB = accF + (size_t)Tn * NS;

    // 2048 waves: (dir, c, batch-group) ; 16 batches per wave via MFMA cols
    mrnn_scan<<<512, 256, 0, stream>>>(x, m, d, Wf, Vf, cf, Wb, Vb, cb, U, accF, accB);
    // one thread per (b,t) = 131072 threads
    mrnn_mix<<<512, 256, 0, stream>>>(x, m, accF, accB, c0, V1w, V2w, Uw, Ub, Ww, Wb_, out);
}

// Round 7
// 117.988 us; speedup vs baseline: 1.3901x; 1.3793x over previous
//
#include <hip/hip_runtime.h>

// Problem constants (B,C,T,H,HI) = (256, 64, 512, 8, 3)
constexpr int Tn = 512;
constexpr int Cn = 64;
constexpr int NS = 16384;   // sequences = B*C; acc planes are [t][seq], seq = b*64+c

// Swap value with partner lane (lane^1) via DPP quad_perm [1,0,3,2] — pure VALU.
__device__ __forceinline__ float dpp_swap1(float v) {
    int i = __builtin_bit_cast(int, v);
    i = __builtin_amdgcn_mov_dpp(i, 0xB1 /*quad_perm 1,0,3,2*/, 0xF, 0xF, true);
    return __builtin_bit_cast(float, i);
}

// Forward 4-step group: carry holds u=4g-1 sample; float4 covers u=4g..4g+3.
#define GRP_F(X4, M4, P4) do {                                        \
    op[0*NS] = step(cx, cm, cd);                                      \
    op[1*NS] = step((X4).x, (M4).x, (P4).x);                          \
    op[2*NS] = step((X4).y, (M4).y, (P4).y);                          \
    op[3*NS] = step((X4).z, (M4).z, (P4).z);                          \
    op += 4*NS;                                                       \
    cx = (X4).w; cm = (M4).w; cd = (P4).w;                            \
} while (0)

// Backward 4-step group at position P=op: carry = u-sample for pos P;
// float4 block supplies u for pos P-1..P-3; leftover .x becomes next carry.
#define GRP_B(X4, M4, P4) do {                                        \
    op[0]      = step(cx, cm, cd);                                    \
    op[-1*NS]  = step((X4).w, (M4).w, (P4).w);                        \
    op[-2*NS]  = step((X4).z, (M4).z, (P4).z);                        \
    op[-3*NS]  = step((X4).y, (M4).y, (P4).y);                        \
    op -= 4*NS;                                                       \
    cx = (X4).x; cm = (M4).x; cd = (P4).x;                            \
} while (0)

// Bidirectional per-channel RNN scan, pair decomposition at 1 wave/SIMD:
// 2 lanes per chain (b,c,dir); lane ph owns hidden rows 4ph..4ph+3. Partner
// rows via 4 DPP quad_perm swaps. Wave = fixed (b,dir) x 32 consecutive c ->
// stores are 128B contiguous. 65536 threads = 1024 waves = 1 wave/SIMD;
// latency hidden by 4-row ILP within the stream. 4-group input prefetch.
__global__ __launch_bounds__(256, 1) void mrnn_scan(
    const float* __restrict__ x, const float* __restrict__ m, const float* __restrict__ d,
    const float* __restrict__ Wf, const float* __restrict__ Vf, const float* __restrict__ cf,
    const float* __restrict__ Wb, const float* __restrict__ Vb, const float* __restrict__ cbk,
    const float* __restrict__ Uu, float* __restrict__ accF, float* __restrict__ accB)
{
    const int g   = blockIdx.x * blockDim.x + threadIdx.x;  // 0..65535
    const int ph  = g & 1;            // which half of the 8 hidden rows
    const int ch  = g >> 1;           // chain id: dir*16384 + b*64 + c
    const int c   = ch & 63;
    const int b   = (ch >> 6) & 255;
    const int dir = ch >> 14;

    const float* W  = dir ? Wb  : Wf;
    const float* V  = dir ? Vb  : Vf;
    const float* cc = dir ? cbk : cf;

    // Per-lane weights. Own rows r = 4ph+j; own cols = 4ph.., partner cols = 4(1-ph)..
    const int ob = 4 * ph;
    const int pb = 4 - ob;
    float Wo[4][4], Wpr[4][4], Vx[4], Vm[4], Vd[4], cb4[4], Uv[4];
    #pragma unroll
    for (int j = 0; j < 4; ++j) {
        const int r = ob + j;
        const float* Wr = W + c*64 + r*8;
        #pragma unroll
        for (int k = 0; k < 4; ++k) {
            Wo[j][k]  = Wr[ob + k];   // multiplies own h[k]
            Wpr[j][k] = Wr[pb + k];   // multiplies partner p[k]
        }
        Vx[j]  = V[c*24 + r*3 + 0];
        Vm[j]  = V[c*24 + r*3 + 1];
        Vd[j]  = V[c*24 + r*3 + 2];
        cb4[j] = cc[c*8 + r];
        Uv[j]  = Uu[c*16 + dir*8 + r];
    }

    float h0 = 0.f, h1 = 0.f, h2 = 0.f, h3 = 0.f;
    float cx, cm, cd;
    const size_t base = ((size_t)b * Cn + c) * Tn;
    const float4* x4p = (const float4*)(x + base);
    const float4* m4p = (const float4*)(m + base);
    const float4* d4p = (const float4*)(d + base);
    float* op = (dir ? accB : accF) + b*64 + c;   // element stride NS per t

    // One recurrence step; returns pair-summed U·h_new (both lanes get it).
    // 3 accumulation trees per row, rows independent -> 4-wide ILP.
    auto step = [&](float xv, float mv, float dv) -> float {
        const float p0 = dpp_swap1(h0);
        const float p1 = dpp_swap1(h1);
        const float p2 = dpp_swap1(h2);
        const float p3 = dpp_swap1(h3);
        float n[4];
        #pragma unroll
        for (int j = 0; j < 4; ++j) {
            float sA = fmaf(Vx[j], xv, cb4[j]);
            float sB = Vm[j] * mv;
            float sC = Vd[j] * dv;
            sA = fmaf(Wo[j][0], h0, sA);
            sB = fmaf(Wo[j][1], h1, sB);
            sC = fmaf(Wo[j][2], h2, sC);
            sA = fmaf(Wo[j][3], h3, sA);
            sB = fmaf(Wpr[j][0], p0, sB);
            sC = fmaf(Wpr[j][1], p1, sC);
            sA = fmaf(Wpr[j][2], p2, sA);
            sB = fmaf(Wpr[j][3], p3, sB);
            n[j] = fmaxf(sA + (sB + sC), 0.f);
        }
        h0 = n[0]; h1 = n[1]; h2 = n[2]; h3 = n[3];
        float dot = fmaf(Uv[0], h0, Uv[1] * h1) + fmaf(Uv[2], h2, Uv[3] * h3);
        dot += dpp_swap1(dot);   // add partner half -> full 8-row dot
        return dot;
    };

    if (dir == 0) {
        // forward: step t uses u = max(t-1,0); 4 groups (16 steps) in flight
        float4 X0 = x4p[0], X1 = x4p[1], X2 = x4p[2], X3 = x4p[3];
        float4 M0 = m4p[0], M1 = m4p[1], M2 = m4p[2], M3 = m4p[3];
        float4 P0 = d4p[0], P1 = d4p[1], P2 = d4p[2], P3 = d4p[3];
        cx = X0.x; cm = M0.x; cd = P0.x;       // u=0 for t=0
        #pragma unroll 1
        for (int i = 0; i < 31; ++i) {
            float4 tX, tM, tP;
            tX = x4p[4*i+4]; tM = m4p[4*i+4]; tP = d4p[4*i+4];
            GRP_F(X0, M0, P0);  X0 = tX; M0 = tM; P0 = tP;
            tX = x4p[4*i+5]; tM = m4p[4*i+5]; tP = d4p[4*i+5];
            GRP_F(X1, M1, P1);  X1 = tX; M1 = tM; P1 = tP;
            tX = x4p[4*i+6]; tM = m4p[4*i+6]; tP = d4p[4*i+6];
            GRP_F(X2, M2, P2);  X2 = tX; M2 = tM; P2 = tP;
            tX = x4p[4*i+7]; tM = m4p[4*i+7]; tP = d4p[4*i+7];
            GRP_F(X3, M3, P3);  X3 = tX; M3 = tM; P3 = tP;
        }
        GRP_F(X0, M0, P0); GRP_F(X1, M1, P1);
        GRP_F(X2, M2, P2); GRP_F(X3, M3, P3);
    } else {
        // backward: pos descends 511..0; s = 511-pos uses u = (s<=1 ? 511 : 512-s)
        op += 511 * NS;
        float4 X0 = x4p[127], X1 = x4p[126], X2 = x4p[125], X3 = x4p[124];
        float4 M0 = m4p[127], M1 = m4p[126], M2 = m4p[125], M3 = m4p[124];
        float4 P0 = d4p[127], P1 = d4p[126], P2 = d4p[125], P3 = d4p[124];
        cx = X0.w; cm = M0.w; cd = P0.w;       // u=511 for pos=511 (s=0)
        #pragma unroll 1
        for (int i = 0; i < 31; ++i) {
            float4 tX, tM, tP;
            tX = x4p[123-4*i]; tM = m4p[123-4*i]; tP = d4p[123-4*i];
            GRP_B(X0, M0, P0);  X0 = tX; M0 = tM; P0 = tP;
            tX = x4p[122-4*i]; tM = m4p[122-4*i]; tP = d4p[122-4*i];
            GRP_B(X1, M1, P1);  X1 = tX; M1 = tM; P1 = tP;
            tX = x4p[121-4*i]; tM = m4p[121-4*i]; tP = d4p[121-4*i];
            GRP_B(X2, M2, P2);  X2 = tX; M2 = tM; P2 = tP;
            tX = x4p[120-4*i]; tM = m4p[120-4*i]; tP = d4p[120-4*i];
            GRP_B(X3, M3, P3);  X3 = tX; M3 = tM; P3 = tP;
        }
        GRP_B(X0, M0, P0); GRP_B(X1, M1, P1);
        GRP_B(X2, M2, P2); GRP_B(X3, M3, P3);
    }
}

// Combine + cross-channel bottleneck MLP. One thread per (b,t).
// x_est = relu(accF + accB + c0); h(3) = relu(V1·x_est + V2·m + Uz·x + U_b);
// out = W_w·h + W_b.
__global__ __launch_bounds__(256, 2) void mrnn_mix(
    const float* __restrict__ x, const float* __restrict__ m,
    const float* __restrict__ accF, const float* __restrict__ accB,
    const float* __restrict__ c0, const float* __restrict__ V1w,
    const float* __restrict__ V2w, const float* __restrict__ Uw,
    const float* __restrict__ Ub, const float* __restrict__ Ww,
    const float* __restrict__ Wbias, float* __restrict__ out)
{
    const int bt = blockIdx.x * 256 + threadIdx.x;   // 0..131071
    const int b = bt >> 9;
    const int t = bt & 511;

    const float4* aF4 = (const float4*)(accF + (size_t)t * NS + b * Cn);
    const float4* aB4 = (const float4*)(accB + (size_t)t * NS + b * Cn);
    const size_t xb = (size_t)b * (Cn * Tn) + t;

    float h0 = Ub[0], h1 = Ub[1], h2 = Ub[2];
    #pragma unroll
    for (int c4 = 0; c4 < 16; ++c4) {
        const float4 fa = aF4[c4];
        const float4 fb = aB4[c4];
        const float fav[4] = {fa.x, fa.y, fa.z, fa.w};
        const float fbv[4] = {fb.x, fb.y, fb.z, fb.w};
        #pragma unroll
        for (int j = 0; j < 4; ++j) {
            const int cch = 4*c4 + j;
            const float xe = fmaxf(fav[j] + fbv[j] + c0[cch], 0.f);
            const float mv = m[xb + (size_t)cch * Tn];
            const float xv = x[xb + (size_t)cch * Tn];
            const float u0 = (cch == 0) ? 0.f : Uw[0*Cn + cch];
            const float u1 = (cch == 1) ? 0.f : Uw[1*Cn + cch];
            const float u2 = (cch == 2) ? 0.f : Uw[2*Cn + cch];
            h0 += V1w[0*Cn + cch]*xe + V2w[0*Cn + cch]*mv + u0*xv;
            h1 += V1w[1*Cn + cch]*xe + V2w[1*Cn + cch]*mv + u1*xv;
            h2 += V1w[2*Cn + cch]*xe + V2w[2*Cn + cch]*mv + u2*xv;
        }
    }
    h0 = fmaxf(h0, 0.f); h1 = fmaxf(h1, 0.f); h2 = fmaxf(h2, 0.f);

    float* opt = out + (size_t)b * (Cn * Tn) + t;
    #pragma unroll
    for (int cch = 0; cch < Cn; ++cch) {
        opt[(size_t)cch * Tn] = Wbias[cch] + Ww[cch*3 + 0]*h0 + Ww[cch*3 + 1]*h1 + Ww[cch*3 + 2]*h2;
    }
}

extern "C" void kernel_launch(void* const* d_in, const int* in_sizes, int n_in,
                              void* d_out, int out_size, void* d_ws, size_t ws_size,
                              hipStream_t stream)
{
    const float* x   = (const float*)d_in[0];
    const float* m   = (const float*)d_in[1];
    const float* d   = (const float*)d_in[2];
    const float* Wf  = (const float*)d_in[3];
    const float* Vf  = (const float*)d_in[4];
    const float* cf  = (const float*)d_in[5];
    const float* Wb  = (const float*)d_in[6];
    const float* Vb  = (const float*)d_in[7];
    const float* cb  = (const float*)d_in[8];
    const float* U   = (const float*)d_in[9];
    const float* c0  = (const float*)d_in[10];
    const float* V1w = (const float*)d_in[11];
    const float* V2w = (const float*)d_in[12];
    const float* Uw  = (const float*)d_in[13];
    const float* Ub  = (const float*)d_in[14];
    const float* Ww  = (const float*)d_in[15];
    const float* Wb_ = (const float*)d_in[16];
    float* out = (float*)d_out;

    // Workspace: accF and accB planes, each Tn*NS floats (33.5 MB), [t][seq].
    float* accF = (float*)d_ws;
    float* accB = accF + (size_t)Tn * NS;

    // 2 lanes * 32768 chains = 65536 threads = 1024 waves = 1 wave/SIMD
    mrnn_scan<<<256, 256, 0, stream>>>(x, m, d, Wf, Vf, cf, Wb, Vb, cb, U, accF, accB);
    // one thread per (b,t) = 131072 threads
    mrnn_mix<<<512, 256, 0, stream>>>(x, m, accF, accB, c0, V1w, V2w, Uw, Ub, Ww, Wb_, out);
}

// Round 9
// 111.219 us; speedup vs baseline: 1.4747x; 1.0609x over previous
//
#include <hip/hip_runtime.h>

// Problem constants (B,C,T,H,HI) = (256, 64, 512, 8, 3)
constexpr int Tn = 512;
constexpr int Cn = 64;
constexpr int NS = 16384;   // sequences = B*C; acc planes are [t][seq], seq=b*64+c

typedef _Float16 h2 __attribute__((ext_vector_type(2)));

__device__ __forceinline__ h2 pkrtz(float lo, float hi) {
    return __builtin_bit_cast(h2, __builtin_amdgcn_cvt_pkrtz(lo, hi));
}
__device__ __forceinline__ float fdot2h(h2 a, h2 b, float c) {
#if __has_builtin(__builtin_amdgcn_fdot2)
    return __builtin_amdgcn_fdot2(a, b, c, false);
#else
    return (float)a.x * (float)b.x + (float)a.y * (float)b.y + c;
#endif
}
template<int CTRL>
__device__ __forceinline__ float dppf(float v) {
    int i = __builtin_bit_cast(int, v);
    i = __builtin_amdgcn_mov_dpp(i, CTRL, 0xF, 0xF, true);
    return __builtin_bit_cast(float, i);
}
template<int CTRL>
__device__ __forceinline__ h2 dpph(h2 v) {
    int i = __builtin_bit_cast(int, v);
    i = __builtin_amdgcn_mov_dpp(i, CTRL, 0xF, 0xF, true);
    return __builtin_bit_cast(h2, i);
}

// Forward 4-step group: carry holds u=4g-1 sample; float4 covers u=4g..4g+3.
// Lane q stores step t=4g+q via one-hot fma select.
#define GRP_F(X4, M4, P4) do {                                        \
    float s0 = step(cx, cm, cd);                                      \
    float s1 = step((X4).x, (M4).x, (P4).x);                          \
    float s2 = step((X4).y, (M4).y, (P4).y);                          \
    float s3 = step((X4).z, (M4).z, (P4).z);                          \
    *opq = fmaf(a3, s3, fmaf(a2, s2, fmaf(a1, s1, a0 * s0)));         \
    opq += 4 * NS;                                                    \
    cx = (X4).w; cm = (M4).w; cd = (P4).w;                            \
} while (0)

// Backward group: steps s=4g..4g+3 at pos=511-4g-k; lane q stores pos=511-4g-q.
#define GRP_B(X4, M4, P4) do {                                        \
    float s0 = step(cx, cm, cd);                                      \
    float s1 = step((X4).w, (M4).w, (P4).w);                          \
    float s2 = step((X4).z, (M4).z, (P4).z);                          \
    float s3 = step((X4).y, (M4).y, (P4).y);                          \
    *opq = fmaf(a3, s3, fmaf(a2, s2, fmaf(a1, s1, a0 * s0)));         \
    opq -= 4 * NS;                                                    \
    cx = (X4).x; cm = (M4).x; cd = (P4).x;                            \
} while (0)

// Bidirectional per-channel RNN scan, quad decomposition with packed-f16 dot2:
// 4 lanes per chain (b,c,dir); lane q owns rows {2q,2q+1}. All 8 h values live
// as one packed f16x2 per lane; cross-lane via 3 quad_perm rotations (DPP).
// Row update = 6 chained v_dot2_f32_f16. 2048 waves = 2 waves/SIMD.
__global__ __launch_bounds__(256, 2) void mrnn_scan(
    const float* __restrict__ x, const float* __restrict__ m, const float* __restrict__ d,
    const float* __restrict__ Wf, const float* __restrict__ Vf, const float* __restrict__ cf,
    const float* __restrict__ Wb, const float* __restrict__ Vb, const float* __restrict__ cbk,
    const float* __restrict__ Uu, float* __restrict__ accF, float* __restrict__ accB)
{
    const int w    = blockIdx.x * 4 + (threadIdx.x >> 6);  // wave id 0..2047
    const int lane = threadIdx.x & 63;
    const int q    = lane & 3;         // lane-in-quad: owns rows 2q, 2q+1
    const int cl   = lane >> 2;        // chain-in-wave: 0..15
    const int dir  = w >> 10;          // 0 = forward, 1 = backward
    const int rem  = w & 1023;
    const int b    = rem >> 2;
    const int c    = (rem & 3) * 16 + cl;

    const float* W  = dir ? Wb  : Wf;
    const float* V  = dir ? Vb  : Vf;
    const float* cc = dir ? cbk : cf;

    const int r0 = 2*q, r1 = 2*q + 1;

    // Rotation-permuted packed weights: after j rotations the lane holds the
    // h-pack of lane s=(q+j)&3 = rows (2s, 2s+1). W{row}j multiplies that pack.
    h2 W00, W01, W02, W03, W10, W11, W12, W13, VA0, VB0, VA1, VB1, UP;
    {
        const float* Wc = W + c*64;
        #pragma unroll
        for (int j = 0; j < 4; ++j) {
            const int s2 = 2 * ((q + j) & 3);
            h2 w0; w0.x = (_Float16)Wc[r0*8 + s2]; w0.y = (_Float16)Wc[r0*8 + s2 + 1];
            h2 w1; w1.x = (_Float16)Wc[r1*8 + s2]; w1.y = (_Float16)Wc[r1*8 + s2 + 1];
            if (j == 0) { W00 = w0; W10 = w1; }
            else if (j == 1) { W01 = w0; W11 = w1; }
            else if (j == 2) { W02 = w0; W12 = w1; }
            else { W03 = w0; W13 = w1; }
        }
        VA0.x = (_Float16)V[c*24 + r0*3 + 0]; VA0.y = (_Float16)V[c*24 + r0*3 + 1];
        VB0.x = (_Float16)V[c*24 + r0*3 + 2]; VB0.y = (_Float16)cc[c*8 + r0];
        VA1.x = (_Float16)V[c*24 + r1*3 + 0]; VA1.y = (_Float16)V[c*24 + r1*3 + 1];
        VB1.x = (_Float16)V[c*24 + r1*3 + 2]; VB1.y = (_Float16)cc[c*8 + r1];
        UP.x  = (_Float16)Uu[c*16 + dir*8 + r0];
        UP.y  = (_Float16)Uu[c*16 + dir*8 + r1];
    }

    // One-hot select weights for the per-lane store slot.
    const float a0 = (q == 0) ? 1.f : 0.f;
    const float a1 = (q == 1) ? 1.f : 0.f;
    const float a2 = (q == 2) ? 1.f : 0.f;
    const float a3 = (q == 3) ? 1.f : 0.f;

    h2 hp = {(_Float16)0.f, (_Float16)0.f};   // own rows' h, packed f16
    float cx, cm, cd;
    const size_t base = ((size_t)b * Cn + c) * Tn;
    const float4* x4p = (const float4*)(x + base);
    const float4* m4p = (const float4*)(m + base);
    const float4* d4p = (const float4*)(d + base);
    const int seq = b * 64 + c;

    // One recurrence step; returns the quad-reduced U·h_new (all lanes).
    auto step = [&](float xv, float mv, float dv) -> float {
        h2 iA = pkrtz(xv, mv);
        h2 iB = pkrtz(dv, 1.0f);
        h2 p0 = hp;
        h2 p1 = dpph<0x39>(p0);   // quad rotate +1
        h2 p2 = dpph<0x39>(p1);
        h2 p3 = dpph<0x39>(p2);
        float r0v = fdot2h(VA0, iA, fdot2h(VB0, iB, 0.f));
        float r1v = fdot2h(VA1, iA, fdot2h(VB1, iB, 0.f));
        r0v = fdot2h(W00, p0, r0v);  r1v = fdot2h(W10, p0, r1v);
        r0v = fdot2h(W01, p1, r0v);  r1v = fdot2h(W11, p1, r1v);
        r0v = fdot2h(W02, p2, r0v);  r1v = fdot2h(W12, p2, r1v);
        r0v = fdot2h(W03, p3, r0v);  r1v = fdot2h(W13, p3, r1v);
        r0v = fmaxf(r0v, 0.f);
        r1v = fmaxf(r1v, 0.f);
        hp = pkrtz(r0v, r1v);
        float du = fdot2h(UP, hp, 0.f);
        du += dppf<0xB1>(du);     // + lane^1
        du += dppf<0x4E>(du);     // + lane^2 -> full 8-row dot, all 4 lanes
        return du;
    };

    if (dir == 0) {
        // forward: step t uses u = max(t-1,0); lane q stores t=4g+q
        float* opq = accF + seq + (size_t)q * NS;
        float4 X0 = x4p[0], X1 = x4p[1], X2 = x4p[2], X3 = x4p[3];
        float4 M0 = m4p[0], M1 = m4p[1], M2 = m4p[2], M3 = m4p[3];
        float4 P0 = d4p[0], P1 = d4p[1], P2 = d4p[2], P3 = d4p[3];
        cx = X0.x; cm = M0.x; cd = P0.x;       // u=0 for t=0
        #pragma unroll 1
        for (int i = 0; i < 31; ++i) {
            float4 tX, tM, tP;
            tX = x4p[4*i+4]; tM = m4p[4*i+4]; tP = d4p[4*i+4];
            GRP_F(X0, M0, P0);  X0 = tX; M0 = tM; P0 = tP;
            tX = x4p[4*i+5]; tM = m4p[4*i+5]; tP = d4p[4*i+5];
            GRP_F(X1, M1, P1);  X1 = tX; M1 = tM; P1 = tP;
            tX = x4p[4*i+6]; tM = m4p[4*i+6]; tP = d4p[4*i+6];
            GRP_F(X2, M2, P2);  X2 = tX; M2 = tM; P2 = tP;
            tX = x4p[4*i+7]; tM = m4p[4*i+7]; tP = d4p[4*i+7];
            GRP_F(X3, M3, P3);  X3 = tX; M3 = tM; P3 = tP;
        }
        GRP_F(X0, M0, P0); GRP_F(X1, M1, P1);
        GRP_F(X2, M2, P2); GRP_F(X3, M3, P3);
    } else {
        // backward: s=0..511 at pos=511-s; u=(s==0?511:512-s); lane q stores pos=511-4g-q
        float* opq = accB + seq + (size_t)(511 - q) * NS;
        float4 X0 = x4p[127], X1 = x4p[126], X2 = x4p[125], X3 = x4p[124];
        float4 M0 = m4p[127], M1 = m4p[126], M2 = m4p[125], M3 = m4p[124];
        float4 P0 = d4p[127], P1 = d4p[126], P2 = d4p[125], P3 = d4p[124];
        cx = X0.w; cm = M0.w; cd = P0.w;       // u=511 for s=0
        #pragma unroll 1
        for (int i = 0; i < 31; ++i) {
            float4 tX, tM, tP;
            tX = x4p[123-4*i]; tM = m4p[123-4*i]; tP = d4p[123-4*i];
            GRP_B(X0, M0, P0);  X0 = tX; M0 = tM; P0 = tP;
            tX = x4p[122-4*i]; tM = m4p[122-4*i]; tP = d4p[122-4*i];
            GRP_B(X1, M1, P1);  X1 = tX; M1 = tM; P1 = tP;
            tX = x4p[121-4*i]; tM = m4p[121-4*i]; tP = d4p[121-4*i];
            GRP_B(X2, M2, P2);  X2 = tX; M2 = tM; P2 = tP;
            tX = x4p[120-4*i]; tM = m4p[120-4*i]; tP = d4p[120-4*i];
            GRP_B(X3, M3, P3);  X3 = tX; M3 = tM; P3 = tP;
        }
        GRP_B(X0, M0, P0); GRP_B(X1, M1, P1);
        GRP_B(X2, M2, P2); GRP_B(X3, M3, P3);
    }
}

// Combine + cross-channel bottleneck MLP. One thread per (b,t).
// x_est = relu(accF + accB + c0); h(3) = relu(V1·x_est + V2·m + Uz·x + U_b);
// out = W_w·h + W_b.
__global__ __launch_bounds__(256, 2) void mrnn_mix(
    const float* __restrict__ x, const float* __restrict__ m,
    const float* __restrict__ accF, const float* __restrict__ accB,
    const float* __restrict__ c0, const float* __restrict__ V1w,
    const float* __restrict__ V2w, const float* __restrict__ Uw,
    const float* __restrict__ Ub, const float* __restrict__ Ww,
    const float* __restrict__ Wbias, float* __restrict__ out)
{
    const int bt = blockIdx.x * 256 + threadIdx.x;   // 0..131071
    const int b = bt >> 9;
    const int t = bt & 511;

    const float4* aF4 = (const float4*)(accF + (size_t)t * NS + b * Cn);
    const float4* aB4 = (const float4*)(accB + (size_t)t * NS + b * Cn);
    const size_t xb = (size_t)b * (Cn * Tn) + t;

    float h0 = Ub[0], h1 = Ub[1], h2 = Ub[2];
    #pragma unroll
    for (int c4 = 0; c4 < 16; ++c4) {
        const float4 fa = aF4[c4];
        const float4 fb = aB4[c4];
        const float fav[4] = {fa.x, fa.y, fa.z, fa.w};
        const float fbv[4] = {fb.x, fb.y, fb.z, fb.w};
        #pragma unroll
        for (int j = 0; j < 4; ++j) {
            const int cch = 4*c4 + j;
            const float xe = fmaxf(fav[j] + fbv[j] + c0[cch], 0.f);
            const float mv = m[xb + (size_t)cch * Tn];
            const float xv = x[xb + (size_t)cch * Tn];
            const float u0 = (cch == 0) ? 0.f : Uw[0*Cn + cch];
            const float u1 = (cch == 1) ? 0.f : Uw[1*Cn + cch];
            const float u2 = (cch == 2) ? 0.f : Uw[2*Cn + cch];
            h0 += V1w[0*Cn + cch]*xe + V2w[0*Cn + cch]*mv + u0*xv;
            h1 += V1w[1*Cn + cch]*xe + V2w[1*Cn + cch]*mv + u1*xv;
            h2 += V1w[2*Cn + cch]*xe + V2w[2*Cn + cch]*mv + u2*xv;
        }
    }
    h0 = fmaxf(h0, 0.f); h1 = fmaxf(h1, 0.f); h2 = fmaxf(h2, 0.f);

    float* opt = out + (size_t)b * (Cn * Tn) + t;
    #pragma unroll
    for (int cch = 0; cch < Cn; ++cch) {
        opt[(size_t)cch * Tn] = Wbias[cch] + Ww[cch*3 + 0]*h0 + Ww[cch*3 + 1]*h1 + Ww[cch*3 + 2]*h2;
    }
}

extern "C" void kernel_launch(void* const* d_in, const int* in_sizes, int n_in,
                              void* d_out, int out_size, void* d_ws, size_t ws_size,
                              hipStream_t stream)
{
    const float* x   = (const float*)d_in[0];
    const float* m   = (const float*)d_in[1];
    const float* d   = (const float*)d_in[2];
    const float* Wf  = (const float*)d_in[3];
    const float* Vf  = (const float*)d_in[4];
    const float* cf  = (const float*)d_in[5];
    const float* Wb  = (const float*)d_in[6];
    const float* Vb  = (const float*)d_in[7];
    const float* cb  = (const float*)d_in[8];
    const float* U   = (const float*)d_in[9];
    const float* c0  = (const float*)d_in[10];
    const float* V1w = (const float*)d_in[11];
    const float* V2w = (const float*)d_in[12];
    const float* Uw  = (const float*)d_in[13];
    const float* Ub  = (const float*)d_in[14];
    const float* Ww  = (const float*)d_in[15];
    const float* Wb_ = (const float*)d_in[16];
    float* out = (float*)d_out;

    // Workspace: accF and accB planes, each Tn*NS floats (33.5 MB), [t][seq].
    float* accF = (float*)d_ws;
    float* accB = accF + (size_t)Tn * NS;

    // 4 lanes * 32768 chains = 131072 threads = 2048 waves = 2 waves/SIMD
    mrnn_scan<<<512, 256, 0, stream>>>(x, m, d, Wf, Vf, cf, Wb, Vb, cb, U, accF, accB);
    // one thread per (b,t) = 131072 threads
    mrnn_mix<<<512, 256, 0, stream>>>(x, m, accF, accB, c0, V1w, V2w, Uw, Ub, Ww, Wb_, out);
}